// Round 7
// baseline (4743.328 us; speedup 1.0000x reference)
//
#include <hip/hip_runtime.h>

#define N_NODES 100000
#define N_EDGES 3200000
static constexpr int NB = (N_NODES + 255) / 256;  // 391

typedef __attribute__((ext_vector_type(2))) float f32x2;

__device__ __forceinline__ float bf2f(unsigned short u) {
  return __uint_as_float(((unsigned)u) << 16);
}
__device__ __forceinline__ unsigned short f2bf(float f) {
  unsigned u = __float_as_uint(f);
  u += 0x7fffu + ((u >> 16) & 1u);
  return (unsigned short)(u >> 16);
}
__device__ __forceinline__ float lo16(unsigned u) { return __uint_as_float(u << 16); }
__device__ __forceinline__ float hi16(unsigned u) { return __uint_as_float(u & 0xffff0000u); }

// ---------------- dtype detection (flag=1: bf16 storage, 0: fp32) ----------------

__global__ void k_detect(const unsigned short* __restrict__ xu, int* __restrict__ flag) {
  __shared__ int cnt;
  if (threadIdx.x == 0) cnt = 0;
  __syncthreads();
  int c = 0;
  for (int i = threadIdx.x; i < 4096; i += 256) {
    float v = fabsf(bf2f(xu[2 * i]));
    if (v >= 1e-4f && v <= 10.f) c++;
  }
  atomicAdd(&cnt, c);
  __syncthreads();
  if (threadIdx.x == 0) *flag = (cnt > 2048) ? 1 : 0;
}

// ---------------- merged prep: weight cvt (24 blocks) | deg zero (NB) | x cvt ----------------

struct CvtArgs {
  const void* src[24];
  int dstoff[24];
  int n[24];
  int tr[24];  // 1: transpose 64x64
};

__global__ void k_prep(CvtArgs a, unsigned short* __restrict__ wb,
                       const void* __restrict__ x, unsigned short* __restrict__ xb,
                       int* __restrict__ deg, const int* __restrict__ flag) {
  int b = blockIdx.x;
  int isbf = *flag;
  if (b < 24) {
    const void* s = a.src[b];
    int n = a.n[b];
    int tr = a.tr[b];
    unsigned short* d = wb + a.dstoff[b];
    for (int i = threadIdx.x; i < n; i += 256) {
      unsigned short v = isbf ? ((const unsigned short*)s)[i] : f2bf(((const float*)s)[i]);
      int di = tr ? ((i & 63) * 64 + (i >> 6)) : i;
      d[di] = v;
    }
  } else if (b < 24 + NB) {
    int i = (b - 24) * 256 + threadIdx.x;
    if (i < N_NODES) deg[i] = 0;
  } else {
    int i = (b - 24 - NB) * 256 + threadIdx.x;  // 8 elems per thread
    if (i * 8 >= N_NODES * 64) return;
    uint4 o;
    if (isbf) {
      o = ((const uint4*)x)[i];
    } else {
      uint4 p = ((const uint4*)x)[2 * i];
      uint4 q = ((const uint4*)x)[2 * i + 1];
      o.x = (unsigned)f2bf(__uint_as_float(p.x)) | ((unsigned)f2bf(__uint_as_float(p.y)) << 16);
      o.y = (unsigned)f2bf(__uint_as_float(p.z)) | ((unsigned)f2bf(__uint_as_float(p.w)) << 16);
      o.z = (unsigned)f2bf(__uint_as_float(q.x)) | ((unsigned)f2bf(__uint_as_float(q.y)) << 16);
      o.w = (unsigned)f2bf(__uint_as_float(q.z)) | ((unsigned)f2bf(__uint_as_float(q.w)) << 16);
    }
    ((uint4*)xb)[i] = o;
  }
}

// ---------------- CSR build ----------------

__global__ void k_hist(const int* __restrict__ dsts, int* __restrict__ deg) {
  int e = blockIdx.x * 256 + threadIdx.x;
  if (e * 4 >= N_EDGES) return;
  int4 d4 = ((const int4*)dsts)[e];
  atomicAdd(&deg[d4.x], 1);
  atomicAdd(&deg[d4.y], 1);
  atomicAdd(&deg[d4.z], 1);
  atomicAdd(&deg[d4.w], 1);
}

__global__ void k_scan1(const int* __restrict__ deg, int* __restrict__ bsum) {
  __shared__ int s[256];
  int i = blockIdx.x * 256 + threadIdx.x;
  int v = (i < N_NODES) ? deg[i] : 0;
  s[threadIdx.x] = v;
  __syncthreads();
  for (int o = 128; o > 0; o >>= 1) {
    if (threadIdx.x < o) s[threadIdx.x] += s[threadIdx.x + o];
    __syncthreads();
  }
  if (threadIdx.x == 0) bsum[blockIdx.x] = s[0];
}

__global__ void k_scan2(const int* __restrict__ bsum, int* __restrict__ bpref,
                        int* __restrict__ off_last) {
  __shared__ int s[512];
  int t = threadIdx.x;
  int v = (t < NB) ? bsum[t] : 0;
  s[t] = v;
  __syncthreads();
  for (int o = 1; o < 512; o <<= 1) {
    int u = (t >= o) ? s[t - o] : 0;
    __syncthreads();
    s[t] += u;
    __syncthreads();
  }
  if (t < NB) bpref[t] = s[t] - v;
  if (t == NB - 1) off_last[0] = s[t];
}

__global__ void k_scan3(const int* __restrict__ deg, const int* __restrict__ bpref,
                        int* __restrict__ off, int* __restrict__ cursor) {
  __shared__ int s[256];
  int t = threadIdx.x;
  int i = blockIdx.x * 256 + t;
  int v = (i < N_NODES) ? deg[i] : 0;
  s[t] = v;
  __syncthreads();
  for (int o = 1; o < 256; o <<= 1) {
    int u = (t >= o) ? s[t - o] : 0;
    __syncthreads();
    s[t] += u;
    __syncthreads();
  }
  if (i < N_NODES) {
    int e = bpref[blockIdx.x] + s[t] - v;
    off[i] = e;
    cursor[i] = e;
  }
}

__global__ void k_scatter(const int* __restrict__ srcs, const int* __restrict__ dsts,
                          int* __restrict__ cursor, int* __restrict__ csr) {
  int e = blockIdx.x * 256 + threadIdx.x;
  if (e * 4 >= N_EDGES) return;
  int4 s4 = ((const int4*)srcs)[e];
  int4 d4 = ((const int4*)dsts)[e];
  csr[atomicAdd(&cursor[d4.x], 1)] = s4.x;
  csr[atomicAdd(&cursor[d4.y], 1)] = s4.y;
  csr[atomicAdd(&cursor[d4.z], 1)] = s4.z;
  csr[atomicAdd(&cursor[d4.w], 1)] = s4.w;
}

// ---------------- K,V projection -> fused fp8 row [K64 | V64], grid-stride ----------------

__global__ __launch_bounds__(256) void k_proj(
    const unsigned short* __restrict__ hin,
    const unsigned short* __restrict__ WkT, const unsigned short* __restrict__ bk,
    const unsigned short* __restrict__ WvT, const unsigned short* __restrict__ bv,
    unsigned char* __restrict__ KVt8) {
  int w = threadIdx.x >> 6;
  int lane = threadIdx.x & 63;
  int stride = gridDim.x * 4;
  const uint4* wkp = (const uint4*)(WkT + (size_t)lane * 64);
  const uint4* wvp = (const uint4*)(WvT + (size_t)lane * 64);
  for (int r = blockIdx.x * 4 + w; r < N_NODES; r += stride) {
    float hv = bf2f(hin[(size_t)r * 64 + lane]);
    float ka = bf2f(bk[lane]);
    float va = bf2f(bv[lane]);
#pragma unroll
    for (int i = 0; i < 8; ++i) {
      uint4 wk = wkp[i];
      uint4 wv = wvp[i];
      float h0, h1;
      h0 = __shfl(hv, i * 8 + 0, 64); h1 = __shfl(hv, i * 8 + 1, 64);
      ka += h0 * lo16(wk.x) + h1 * hi16(wk.x); va += h0 * lo16(wv.x) + h1 * hi16(wv.x);
      h0 = __shfl(hv, i * 8 + 2, 64); h1 = __shfl(hv, i * 8 + 3, 64);
      ka += h0 * lo16(wk.y) + h1 * hi16(wk.y); va += h0 * lo16(wv.y) + h1 * hi16(wv.y);
      h0 = __shfl(hv, i * 8 + 4, 64); h1 = __shfl(hv, i * 8 + 5, 64);
      ka += h0 * lo16(wk.z) + h1 * hi16(wk.z); va += h0 * lo16(wv.z) + h1 * hi16(wv.z);
      h0 = __shfl(hv, i * 8 + 6, 64); h1 = __shfl(hv, i * 8 + 7, 64);
      ka += h0 * lo16(wk.w) + h1 * hi16(wk.w); va += h0 * lo16(wv.w) + h1 * hi16(wv.w);
    }
    int pk = __builtin_amdgcn_cvt_pk_fp8_f32(ka, ka, 0, false);
    int pv = __builtin_amdgcn_cvt_pk_fp8_f32(va, va, 0, false);
    KVt8[(size_t)r * 128 + lane] = (unsigned char)(pk & 0xff);
    KVt8[(size_t)r * 128 + 64 + lane] = (unsigned char)(pv & 0xff);
  }
}

// ---------------- edge pass, C=64: no-max softmax (clamped), grid-stride ----------------

template <bool RES>
__global__ __launch_bounds__(256, 6) void k_edge64(
    const int* __restrict__ off, const int* __restrict__ csr,
    const unsigned short* __restrict__ hin,
    const unsigned short* __restrict__ WqT, const unsigned short* __restrict__ bq,
    const unsigned short* __restrict__ WsT, const unsigned short* __restrict__ bs,
    const unsigned char* __restrict__ KVt8,
    unsigned short* __restrict__ hout) {
  __shared__ float qs[4][64];
  int w = threadIdx.x >> 6;
  int lane = threadIdx.x & 63;
  int stride = gridDim.x * 4;
  for (int wid = blockIdx.x * 4 + w; wid < N_NODES; wid += stride) {
    int base = off[wid];
    int deg = off[wid + 1] - base;
    float hv = bf2f(hin[(size_t)wid * 64 + lane]);
    // ---- q projection ----
    {
      float q = bf2f(bq[lane]);
      const uint4* wqp = (const uint4*)(WqT + (size_t)lane * 64);
#pragma unroll
      for (int i = 0; i < 8; ++i) {
        uint4 wq = wqp[i];
        float h0, h1;
        h0 = __shfl(hv, i * 8 + 0, 64); h1 = __shfl(hv, i * 8 + 1, 64);
        q += h0 * lo16(wq.x) + h1 * hi16(wq.x);
        h0 = __shfl(hv, i * 8 + 2, 64); h1 = __shfl(hv, i * 8 + 3, 64);
        q += h0 * lo16(wq.y) + h1 * hi16(wq.y);
        h0 = __shfl(hv, i * 8 + 4, 64); h1 = __shfl(hv, i * 8 + 5, 64);
        q += h0 * lo16(wq.z) + h1 * hi16(wq.z);
        h0 = __shfl(hv, i * 8 + 6, 64); h1 = __shfl(hv, i * 8 + 7, 64);
        q += h0 * lo16(wq.w) + h1 * hi16(wq.w);
      }
      qs[w][lane] = q;  // wave-local write->read
    }
    float ssl = 0.f, acc0 = 0.f, acc1 = 0.f;
    const float4* qv = (const float4*)qs[w];

    for (int j0 = 0; j0 < deg; j0 += 64) {
      int cnt = min(64, deg - j0);
      int src = csr[base + ((lane < cnt) ? (j0 + lane) : 0)];
      // ---- phase 1: my edge's score; K = first 64 B of the row ----
      const uint4* kp = (const uint4*)(KVt8 + (size_t)src * 128);
      float d0 = 0.f, d1 = 0.f, d2 = 0.f, d3 = 0.f;
#pragma unroll
      for (int i = 0; i < 4; ++i) {
        uint4 kk = kp[i];
        float4 qa = qv[4 * i + 0];
        f32x2 p0 = __builtin_amdgcn_cvt_pk_f32_fp8((int)kk.x, false);
        f32x2 p1 = __builtin_amdgcn_cvt_pk_f32_fp8((int)kk.x, true);
        d0 += qa.x * p0[0]; d1 += qa.y * p0[1]; d2 += qa.z * p1[0]; d3 += qa.w * p1[1];
        qa = qv[4 * i + 1];
        p0 = __builtin_amdgcn_cvt_pk_f32_fp8((int)kk.y, false);
        p1 = __builtin_amdgcn_cvt_pk_f32_fp8((int)kk.y, true);
        d0 += qa.x * p0[0]; d1 += qa.y * p0[1]; d2 += qa.z * p1[0]; d3 += qa.w * p1[1];
        qa = qv[4 * i + 2];
        p0 = __builtin_amdgcn_cvt_pk_f32_fp8((int)kk.z, false);
        p1 = __builtin_amdgcn_cvt_pk_f32_fp8((int)kk.z, true);
        d0 += qa.x * p0[0]; d1 += qa.y * p0[1]; d2 += qa.z * p1[0]; d3 += qa.w * p1[1];
        qa = qv[4 * i + 3];
        p0 = __builtin_amdgcn_cvt_pk_f32_fp8((int)kk.w, false);
        p1 = __builtin_amdgcn_cvt_pk_f32_fp8((int)kk.w, true);
        d0 += qa.x * p0[0]; d1 += qa.y * p0[1]; d2 += qa.z * p1[0]; d3 += qa.w * p1[1];
      }
      float sc = ((d0 + d1) + (d2 + d3)) * 0.125f;  // /sqrt(64)
      sc = fminf(fmaxf(sc, -60.f), 60.f);           // exp stays finite in f32
      float al = (lane < cnt) ? __expf(sc) : 0.f;   // no max needed: shift-invariant
      ssl += al;
      // ---- phase 2: 4-unrolled dim-per-lane aggregation (V in same 128-B line) ----
      for (int jj = 0; jj < cnt; jj += 4) {
        int s0 = __shfl(src, jj + 0, 64);
        int s1 = __shfl(src, jj + 1, 64);
        int s2 = __shfl(src, jj + 2, 64);
        int s3 = __shfl(src, jj + 3, 64);
        float a0 = __shfl(al, jj + 0, 64);
        float a1 = __shfl(al, jj + 1, 64);
        float a2 = __shfl(al, jj + 2, 64);
        float a3 = __shfl(al, jj + 3, 64);
        int v0 = KVt8[(size_t)s0 * 128 + 64 + lane];
        int v1 = KVt8[(size_t)s1 * 128 + 64 + lane];
        int v2 = KVt8[(size_t)s2 * 128 + 64 + lane];
        int v3 = KVt8[(size_t)s3 * 128 + 64 + lane];
        acc0 += a0 * __builtin_amdgcn_cvt_f32_fp8(v0, 0);
        acc1 += a1 * __builtin_amdgcn_cvt_f32_fp8(v1, 0);
        acc0 += a2 * __builtin_amdgcn_cvt_f32_fp8(v2, 0);
        acc1 += a3 * __builtin_amdgcn_cvt_f32_fp8(v3, 0);
      }
    }
    // ---- final: sum-of-alpha butterfly (once per node) ----
    float ssum = ssl;
    ssum += __shfl_xor(ssum, 32, 64);
    ssum += __shfl_xor(ssum, 16, 64);
    ssum += __shfl_xor(ssum, 8, 64);
    ssum += __shfl_xor(ssum, 4, 64);
    ssum += __shfl_xor(ssum, 2, 64);
    ssum += __shfl_xor(ssum, 1, 64);
    // ---- skip projection ----
    float sk = bf2f(bs[lane]);
    {
      const uint4* wsp = (const uint4*)(WsT + (size_t)lane * 64);
#pragma unroll
      for (int i = 0; i < 8; ++i) {
        uint4 ws = wsp[i];
        float h0, h1;
        h0 = __shfl(hv, i * 8 + 0, 64); h1 = __shfl(hv, i * 8 + 1, 64);
        sk += h0 * lo16(ws.x) + h1 * hi16(ws.x);
        h0 = __shfl(hv, i * 8 + 2, 64); h1 = __shfl(hv, i * 8 + 3, 64);
        sk += h0 * lo16(ws.y) + h1 * hi16(ws.y);
        h0 = __shfl(hv, i * 8 + 4, 64); h1 = __shfl(hv, i * 8 + 5, 64);
        sk += h0 * lo16(ws.z) + h1 * hi16(ws.z);
        h0 = __shfl(hv, i * 8 + 6, 64); h1 = __shfl(hv, i * 8 + 7, 64);
        sk += h0 * lo16(ws.w) + h1 * hi16(ws.w);
      }
    }
    float val = (acc0 + acc1) / (ssum + 1e-16f) + sk;
    if (RES) val += hv;
    hout[(size_t)wid * 64 + lane] = f2bf(tanhf(val));
  }
}

// ---------------- layer 3 projections (C=3): thread per node ----------------

__global__ __launch_bounds__(256) void k_gemm3(
    const unsigned short* __restrict__ hin,
    const unsigned short* __restrict__ Wq, const unsigned short* __restrict__ bq,
    const unsigned short* __restrict__ Wk, const unsigned short* __restrict__ bk,
    const unsigned short* __restrict__ Wv, const unsigned short* __restrict__ bv,
    const unsigned short* __restrict__ Ws, const unsigned short* __restrict__ bs,
    float* __restrict__ Q3, float* __restrict__ S3, uint4* __restrict__ KV3) {
  int d = blockIdx.x * 256 + threadIdx.x;
  if (d >= N_NODES) return;
  float q[3], kk[3], vv[3], ss[3];
  for (int c = 0; c < 3; ++c) {
    q[c] = bf2f(bq[c]);
    kk[c] = bf2f(bk[c]);
    vv[c] = bf2f(bv[c]);
    ss[c] = bf2f(bs[c]);
  }
  for (int j = 0; j < 64; ++j) {
    float hj = bf2f(hin[(size_t)d * 64 + j]);
    for (int c = 0; c < 3; ++c) {
      q[c] += hj * bf2f(Wq[j * 3 + c]);
      kk[c] += hj * bf2f(Wk[j * 3 + c]);
      vv[c] += hj * bf2f(Wv[j * 3 + c]);
      ss[c] += hj * bf2f(Ws[j * 3 + c]);
    }
  }
  for (int c = 0; c < 3; ++c) {
    Q3[d * 4 + c] = q[c];
    S3[d * 4 + c] = ss[c];
  }
  uint4 pk;
  pk.x = (unsigned)f2bf(kk[0]) | ((unsigned)f2bf(vv[0]) << 16);
  pk.y = (unsigned)f2bf(kk[1]) | ((unsigned)f2bf(vv[1]) << 16);
  pk.z = (unsigned)f2bf(kk[2]) | ((unsigned)f2bf(vv[2]) << 16);
  pk.w = 0;
  KV3[d] = pk;
}

// ---------------- edge pass, C=3: wave per dst, no-max, grid-stride ----------------

__global__ __launch_bounds__(256) void k_edge3(
    const int* __restrict__ off, const int* __restrict__ csr,
    const float* __restrict__ Q3, const float* __restrict__ S3,
    const uint4* __restrict__ KV3, const void* __restrict__ noise,
    void* __restrict__ out, const int* __restrict__ flag) {
  int w = threadIdx.x >> 6;
  int lane = threadIdx.x & 63;
  int stride = gridDim.x * 4;
  const float isq = 0.57735026919f;  // 1/sqrt(3)
  for (int wid = blockIdx.x * 4 + w; wid < N_NODES; wid += stride) {
    int base = off[wid];
    int deg = off[wid + 1] - base;
    float q0 = Q3[wid * 4], q1 = Q3[wid * 4 + 1], q2 = Q3[wid * 4 + 2];
    float ps = 0.f, p0 = 0.f, p1 = 0.f, p2 = 0.f;
    for (int j0 = 0; j0 < deg; j0 += 64) {
      int cnt = min(64, deg - j0);
      int src = csr[base + ((lane < cnt) ? (j0 + lane) : 0)];
      uint4 kv = KV3[src];  // 16-B gather from 1.6 MB (L2-resident)
      float sc = (q0 * lo16(kv.x) + q1 * lo16(kv.y) + q2 * lo16(kv.z)) * isq;
      sc = fminf(fmaxf(sc, -60.f), 60.f);
      float al = (lane < cnt) ? __expf(sc) : 0.f;
      ps += al;
      p0 += al * hi16(kv.x);
      p1 += al * hi16(kv.y);
      p2 += al * hi16(kv.z);
    }
#pragma unroll
    for (int o = 32; o > 0; o >>= 1) {
      ps += __shfl_xor(ps, o, 64);
      p0 += __shfl_xor(p0, o, 64);
      p1 += __shfl_xor(p1, o, 64);
      p2 += __shfl_xor(p2, o, 64);
    }
    if (lane == 0) {
      float inv = 1.f / (ps + 1e-16f);
      int isbf = *flag;
      float n0, n1, n2;
      if (isbf) {
        const unsigned short* nu = (const unsigned short*)noise;
        n0 = bf2f(nu[wid * 3 + 0]);
        n1 = bf2f(nu[wid * 3 + 1]);
        n2 = bf2f(nu[wid * 3 + 2]);
      } else {
        const float* nf = (const float*)noise;
        n0 = nf[wid * 3 + 0];
        n1 = nf[wid * 3 + 1];
        n2 = nf[wid * 3 + 2];
      }
      float r0 = p0 * inv + S3[wid * 4 + 0] + 0.1f * n0;
      float r1 = p1 * inv + S3[wid * 4 + 1] + 0.1f * n1;
      float r2 = p2 * inv + S3[wid * 4 + 2] + 0.1f * n2;
      if (isbf) {
        unsigned short* ou = (unsigned short*)out;
        ou[wid * 3 + 0] = f2bf(r0);
        ou[wid * 3 + 1] = f2bf(r1);
        ou[wid * 3 + 2] = f2bf(r2);
      } else {
        float* of = (float*)out;
        of[wid * 3 + 0] = r0;
        of[wid * 3 + 1] = r1;
        of[wid * 3 + 2] = r2;
      }
    }
  }
}

// ---------------- launch ----------------

extern "C" void kernel_launch(void* const* d_in, const int* in_sizes, int n_in,
                              void* d_out, int out_size, void* d_ws, size_t ws_size,
                              hipStream_t stream) {
  const int* ei = (const int*)d_in[1];
  const int* srcs = ei;
  const int* dsts = ei + N_EDGES;

  // Workspace (NEED ~38.9 MB):
  //   off @0 | csr @400128 | h @13200128 (bf16) | KVt8 @26000128 ([K64|V64] u8 rows)
  //   (KVt8 region aliases CSR scratch pre-proj; Q3/S3/KV3 in layer 3)
  //   wb @38800128 (layers 1-2 weights TRANSPOSED) | flag @38868480
  char* w = (char*)d_ws;
  int* off = (int*)w;
  int* csr = (int*)(w + 400128);
  unsigned short* h = (unsigned short*)(w + 13200128);
  char* kvbase = w + 26000128;
  unsigned char* KVt8 = (unsigned char*)kvbase;
  int* deg = (int*)kvbase;
  int* cursor = (int*)(kvbase + 524288);
  int* bsum = (int*)(kvbase + 1048576);
  int* bpref = (int*)(kvbase + 1056768);
  float* Q3 = (float*)kvbase;
  float* S3 = (float*)(kvbase + 2097152);
  uint4* KV3 = (uint4*)(kvbase + 4194304);
  unsigned short* wb = (unsigned short*)(w + 38800128);
  int* flag = (int*)(w + 38868480);
  const size_t NEED = 38868608;
  if (ws_size < NEED) return;

  unsigned short *Wb[3][4], *Bb[3][4];
  CvtArgs ca;
  {
    int o = 0, idx = 0;
    for (int l = 0; l < 3; ++l) {
      int dout = (l == 2) ? 3 : 64;
      for (int p = 0; p < 4; ++p) {
        ca.src[idx] = d_in[3 + l * 8 + p * 2];
        ca.dstoff[idx] = o;
        ca.n[idx] = 64 * dout;
        ca.tr[idx] = (l < 2) ? 1 : 0;  // layers 1-2: store W^T
        Wb[l][p] = wb + o;
        o += 64 * dout;
        idx++;
        ca.src[idx] = d_in[3 + l * 8 + p * 2 + 1];
        ca.dstoff[idx] = o;
        ca.n[idx] = dout;
        ca.tr[idx] = 0;
        Bb[l][p] = wb + o;
        o += dout;
        idx++;
      }
    }
  }

  k_detect<<<1, 256, 0, stream>>>((const unsigned short*)d_in[0], flag);
  // merged: weights (24) | deg zero (NB) | x cvt (3125)
  k_prep<<<24 + NB + N_NODES * 64 / 8 / 256, 256, 0, stream>>>(ca, wb, d_in[0], h, deg, flag);

  k_hist<<<N_EDGES / 4 / 256, 256, 0, stream>>>(dsts, deg);
  k_scan1<<<NB, 256, 0, stream>>>(deg, bsum);
  k_scan2<<<1, 512, 0, stream>>>(bsum, bpref, off + N_NODES);
  k_scan3<<<NB, 256, 0, stream>>>(deg, bpref, off, cursor);
  k_scatter<<<N_EDGES / 4 / 256, 256, 0, stream>>>(srcs, dsts, cursor, csr);

  const int GP = 1536;  // persistent-style grids: 6 blocks/CU
  // layer 1
  k_proj<<<GP, 256, 0, stream>>>(h, Wb[0][1], Bb[0][1], Wb[0][2], Bb[0][2], KVt8);
  k_edge64<false><<<GP, 256, 0, stream>>>(off, csr, h, Wb[0][0], Bb[0][0],
                                          Wb[0][3], Bb[0][3], KVt8, h);
  // layer 2
  k_proj<<<GP, 256, 0, stream>>>(h, Wb[1][1], Bb[1][1], Wb[1][2], Bb[1][2], KVt8);
  k_edge64<true><<<GP, 256, 0, stream>>>(off, csr, h, Wb[1][0], Bb[1][0],
                                         Wb[1][3], Bb[1][3], KVt8, h);
  // layer 3
  k_gemm3<<<NB, 256, 0, stream>>>(h, Wb[2][0], Bb[2][0], Wb[2][1], Bb[2][1],
                                  Wb[2][2], Bb[2][2], Wb[2][3], Bb[2][3], Q3, S3, KV3);
  k_edge3<<<GP, 256, 0, stream>>>(off, csr, Q3, S3, KV3, d_in[2], d_out, flag);
}

// Round 8
// 1591.440 us; speedup vs baseline: 2.9805x; 2.9805x over previous
//
#include <hip/hip_runtime.h>

#define N_NODES 100000
#define N_EDGES 3200000
static constexpr int NB = (N_NODES + 255) / 256;  // 391

typedef __attribute__((ext_vector_type(2))) float f32x2;

__device__ __forceinline__ float bf2f(unsigned short u) {
  return __uint_as_float(((unsigned)u) << 16);
}
__device__ __forceinline__ unsigned short f2bf(float f) {
  unsigned u = __float_as_uint(f);
  u += 0x7fffu + ((u >> 16) & 1u);
  return (unsigned short)(u >> 16);
}
__device__ __forceinline__ float lo16(unsigned u) { return __uint_as_float(u << 16); }
__device__ __forceinline__ float hi16(unsigned u) { return __uint_as_float(u & 0xffff0000u); }

// ---------------- dtype detection (flag=1: bf16 storage, 0: fp32) ----------------

__global__ void k_detect(const unsigned short* __restrict__ xu, int* __restrict__ flag) {
  __shared__ int cnt;
  if (threadIdx.x == 0) cnt = 0;
  __syncthreads();
  int c = 0;
  for (int i = threadIdx.x; i < 4096; i += 256) {
    float v = fabsf(bf2f(xu[2 * i]));
    if (v >= 1e-4f && v <= 10.f) c++;
  }
  atomicAdd(&cnt, c);
  __syncthreads();
  if (threadIdx.x == 0) *flag = (cnt > 2048) ? 1 : 0;
}

// ---------------- merged prep: weight cvt (24 blocks) | deg zero (NB) | x cvt ----------------

struct CvtArgs {
  const void* src[24];
  int dstoff[24];
  int n[24];
  int tr[24];  // 1: transpose 64x64
};

__global__ void k_prep(CvtArgs a, unsigned short* __restrict__ wb,
                       const void* __restrict__ x, unsigned short* __restrict__ xb,
                       int* __restrict__ deg, const int* __restrict__ flag) {
  int b = blockIdx.x;
  int isbf = *flag;
  if (b < 24) {
    const void* s = a.src[b];
    int n = a.n[b];
    int tr = a.tr[b];
    unsigned short* d = wb + a.dstoff[b];
    for (int i = threadIdx.x; i < n; i += 256) {
      unsigned short v = isbf ? ((const unsigned short*)s)[i] : f2bf(((const float*)s)[i]);
      int di = tr ? ((i & 63) * 64 + (i >> 6)) : i;
      d[di] = v;
    }
  } else if (b < 24 + NB) {
    int i = (b - 24) * 256 + threadIdx.x;
    if (i < N_NODES) deg[i] = 0;
  } else {
    int i = (b - 24 - NB) * 256 + threadIdx.x;  // 8 elems per thread
    if (i * 8 >= N_NODES * 64) return;
    uint4 o;
    if (isbf) {
      o = ((const uint4*)x)[i];
    } else {
      uint4 p = ((const uint4*)x)[2 * i];
      uint4 q = ((const uint4*)x)[2 * i + 1];
      o.x = (unsigned)f2bf(__uint_as_float(p.x)) | ((unsigned)f2bf(__uint_as_float(p.y)) << 16);
      o.y = (unsigned)f2bf(__uint_as_float(p.z)) | ((unsigned)f2bf(__uint_as_float(p.w)) << 16);
      o.z = (unsigned)f2bf(__uint_as_float(q.x)) | ((unsigned)f2bf(__uint_as_float(q.y)) << 16);
      o.w = (unsigned)f2bf(__uint_as_float(q.z)) | ((unsigned)f2bf(__uint_as_float(q.w)) << 16);
    }
    ((uint4*)xb)[i] = o;
  }
}

// ---------------- CSR build ----------------

__global__ void k_hist(const int* __restrict__ dsts, int* __restrict__ deg) {
  int e = blockIdx.x * 256 + threadIdx.x;
  if (e * 4 >= N_EDGES) return;
  int4 d4 = ((const int4*)dsts)[e];
  atomicAdd(&deg[d4.x], 1);
  atomicAdd(&deg[d4.y], 1);
  atomicAdd(&deg[d4.z], 1);
  atomicAdd(&deg[d4.w], 1);
}

__global__ void k_scan1(const int* __restrict__ deg, int* __restrict__ bsum) {
  __shared__ int s[256];
  int i = blockIdx.x * 256 + threadIdx.x;
  int v = (i < N_NODES) ? deg[i] : 0;
  s[threadIdx.x] = v;
  __syncthreads();
  for (int o = 128; o > 0; o >>= 1) {
    if (threadIdx.x < o) s[threadIdx.x] += s[threadIdx.x + o];
    __syncthreads();
  }
  if (threadIdx.x == 0) bsum[blockIdx.x] = s[0];
}

__global__ void k_scan2(const int* __restrict__ bsum, int* __restrict__ bpref,
                        int* __restrict__ off_last) {
  __shared__ int s[512];
  int t = threadIdx.x;
  int v = (t < NB) ? bsum[t] : 0;
  s[t] = v;
  __syncthreads();
  for (int o = 1; o < 512; o <<= 1) {
    int u = (t >= o) ? s[t - o] : 0;
    __syncthreads();
    s[t] += u;
    __syncthreads();
  }
  if (t < NB) bpref[t] = s[t] - v;
  if (t == NB - 1) off_last[0] = s[t];
}

__global__ void k_scan3(const int* __restrict__ deg, const int* __restrict__ bpref,
                        int* __restrict__ off, int* __restrict__ cursor) {
  __shared__ int s[256];
  int t = threadIdx.x;
  int i = blockIdx.x * 256 + t;
  int v = (i < N_NODES) ? deg[i] : 0;
  s[t] = v;
  __syncthreads();
  for (int o = 1; o < 256; o <<= 1) {
    int u = (t >= o) ? s[t - o] : 0;
    __syncthreads();
    s[t] += u;
    __syncthreads();
  }
  if (i < N_NODES) {
    int e = bpref[blockIdx.x] + s[t] - v;
    off[i] = e;
    cursor[i] = e;
  }
}

__global__ void k_scatter(const int* __restrict__ srcs, const int* __restrict__ dsts,
                          int* __restrict__ cursor, int* __restrict__ csr) {
  int e = blockIdx.x * 256 + threadIdx.x;
  if (e * 4 >= N_EDGES) return;
  int4 s4 = ((const int4*)srcs)[e];
  int4 d4 = ((const int4*)dsts)[e];
  csr[atomicAdd(&cursor[d4.x], 1)] = s4.x;
  csr[atomicAdd(&cursor[d4.y], 1)] = s4.y;
  csr[atomicAdd(&cursor[d4.z], 1)] = s4.z;
  csr[atomicAdd(&cursor[d4.w], 1)] = s4.w;
}

// ---------------- Q,K,V projection: wave per row -> Qt bf16 + fused fp8 [K64|V64] ----------------

__global__ __launch_bounds__(256) void k_proj(
    const unsigned short* __restrict__ hin,
    const unsigned short* __restrict__ WqT, const unsigned short* __restrict__ bq,
    const unsigned short* __restrict__ WkT, const unsigned short* __restrict__ bk,
    const unsigned short* __restrict__ WvT, const unsigned short* __restrict__ bv,
    unsigned short* __restrict__ Qt, unsigned char* __restrict__ KVt8) {
  int r = blockIdx.x * 4 + (threadIdx.x >> 6);
  int lane = threadIdx.x & 63;
  float hv = bf2f(hin[(size_t)r * 64 + lane]);
  float qa = bf2f(bq[lane]);
  float ka = bf2f(bk[lane]);
  float va = bf2f(bv[lane]);
  const uint4* wqp = (const uint4*)(WqT + (size_t)lane * 64);
  const uint4* wkp = (const uint4*)(WkT + (size_t)lane * 64);
  const uint4* wvp = (const uint4*)(WvT + (size_t)lane * 64);
#pragma unroll
  for (int i = 0; i < 8; ++i) {
    uint4 wq = wqp[i];
    uint4 wk = wkp[i];
    uint4 wv = wvp[i];
    float h0, h1;
    h0 = __shfl(hv, i * 8 + 0, 64); h1 = __shfl(hv, i * 8 + 1, 64);
    qa += h0 * lo16(wq.x) + h1 * hi16(wq.x);
    ka += h0 * lo16(wk.x) + h1 * hi16(wk.x);
    va += h0 * lo16(wv.x) + h1 * hi16(wv.x);
    h0 = __shfl(hv, i * 8 + 2, 64); h1 = __shfl(hv, i * 8 + 3, 64);
    qa += h0 * lo16(wq.y) + h1 * hi16(wq.y);
    ka += h0 * lo16(wk.y) + h1 * hi16(wk.y);
    va += h0 * lo16(wv.y) + h1 * hi16(wv.y);
    h0 = __shfl(hv, i * 8 + 4, 64); h1 = __shfl(hv, i * 8 + 5, 64);
    qa += h0 * lo16(wq.z) + h1 * hi16(wq.z);
    ka += h0 * lo16(wk.z) + h1 * hi16(wk.z);
    va += h0 * lo16(wv.z) + h1 * hi16(wv.z);
    h0 = __shfl(hv, i * 8 + 6, 64); h1 = __shfl(hv, i * 8 + 7, 64);
    qa += h0 * lo16(wq.w) + h1 * hi16(wq.w);
    ka += h0 * lo16(wk.w) + h1 * hi16(wk.w);
    va += h0 * lo16(wv.w) + h1 * hi16(wv.w);
  }
  Qt[(size_t)r * 64 + lane] = f2bf(qa);
  int pk = __builtin_amdgcn_cvt_pk_fp8_f32(ka, ka, 0, false);
  int pv = __builtin_amdgcn_cvt_pk_fp8_f32(va, va, 0, false);
  KVt8[(size_t)r * 128 + lane] = (unsigned char)(pk & 0xff);
  KVt8[(size_t)r * 128 + 64 + lane] = (unsigned char)(pv & 0xff);
}

// ---------------- edge pass, C=64: precomputed q, no-max softmax ----------------

template <bool RES>
__global__ __launch_bounds__(256) void k_edge64(
    const int* __restrict__ off, const int* __restrict__ csr,
    const unsigned short* __restrict__ hin, const unsigned short* __restrict__ Qt,
    const unsigned short* __restrict__ WsT, const unsigned short* __restrict__ bs,
    const unsigned char* __restrict__ KVt8,
    unsigned short* __restrict__ hout) {
  __shared__ float qs[4][64];
  int w = threadIdx.x >> 6;
  int lane = threadIdx.x & 63;
  int wid = blockIdx.x * 4 + w;
  int base = off[wid];
  int deg = off[wid + 1] - base;
  float hv = bf2f(hin[(size_t)wid * 64 + lane]);
  qs[w][lane] = bf2f(Qt[(size_t)wid * 64 + lane]);  // wave-local write->read

  float ssl = 0.f, acc0 = 0.f, acc1 = 0.f;
  const float4* qv = (const float4*)qs[w];

  for (int j0 = 0; j0 < deg; j0 += 64) {
    int cnt = min(64, deg - j0);
    int src = csr[base + ((lane < cnt) ? (j0 + lane) : 0)];
    // ---- phase 1: my edge's score; K = first 64 B of the 128-B row ----
    const uint4* kp = (const uint4*)(KVt8 + (size_t)src * 128);
    float d0 = 0.f, d1 = 0.f, d2 = 0.f, d3 = 0.f;
#pragma unroll
    for (int i = 0; i < 4; ++i) {
      uint4 kk = kp[i];
      float4 qa = qv[4 * i + 0];
      f32x2 p0 = __builtin_amdgcn_cvt_pk_f32_fp8((int)kk.x, false);
      f32x2 p1 = __builtin_amdgcn_cvt_pk_f32_fp8((int)kk.x, true);
      d0 += qa.x * p0[0]; d1 += qa.y * p0[1]; d2 += qa.z * p1[0]; d3 += qa.w * p1[1];
      qa = qv[4 * i + 1];
      p0 = __builtin_amdgcn_cvt_pk_f32_fp8((int)kk.y, false);
      p1 = __builtin_amdgcn_cvt_pk_f32_fp8((int)kk.y, true);
      d0 += qa.x * p0[0]; d1 += qa.y * p0[1]; d2 += qa.z * p1[0]; d3 += qa.w * p1[1];
      qa = qv[4 * i + 2];
      p0 = __builtin_amdgcn_cvt_pk_f32_fp8((int)kk.z, false);
      p1 = __builtin_amdgcn_cvt_pk_f32_fp8((int)kk.z, true);
      d0 += qa.x * p0[0]; d1 += qa.y * p0[1]; d2 += qa.z * p1[0]; d3 += qa.w * p1[1];
      qa = qv[4 * i + 3];
      p0 = __builtin_amdgcn_cvt_pk_f32_fp8((int)kk.w, false);
      p1 = __builtin_amdgcn_cvt_pk_f32_fp8((int)kk.w, true);
      d0 += qa.x * p0[0]; d1 += qa.y * p0[1]; d2 += qa.z * p1[0]; d3 += qa.w * p1[1];
    }
    float sc = ((d0 + d1) + (d2 + d3)) * 0.125f;  // /sqrt(64)
    sc = fminf(fmaxf(sc, -60.f), 60.f);           // exp finite in f32
    float al = (lane < cnt) ? __expf(sc) : 0.f;   // shift-invariant: no max pass
    ssl += al;
    // ---- phase 2: 8-unrolled dim-per-lane aggregation (al=0 pads tail) ----
    int cnt8 = (cnt + 7) & ~7;
    for (int jj = 0; jj < cnt8; jj += 8) {
      int s0 = __shfl(src, jj + 0, 64);
      int s1 = __shfl(src, jj + 1, 64);
      int s2 = __shfl(src, jj + 2, 64);
      int s3 = __shfl(src, jj + 3, 64);
      int s4 = __shfl(src, jj + 4, 64);
      int s5 = __shfl(src, jj + 5, 64);
      int s6 = __shfl(src, jj + 6, 64);
      int s7 = __shfl(src, jj + 7, 64);
      float a0 = __shfl(al, jj + 0, 64);
      float a1 = __shfl(al, jj + 1, 64);
      float a2 = __shfl(al, jj + 2, 64);
      float a3 = __shfl(al, jj + 3, 64);
      float a4 = __shfl(al, jj + 4, 64);
      float a5 = __shfl(al, jj + 5, 64);
      float a6 = __shfl(al, jj + 6, 64);
      float a7 = __shfl(al, jj + 7, 64);
      int v0 = KVt8[(size_t)s0 * 128 + 64 + lane];
      int v1 = KVt8[(size_t)s1 * 128 + 64 + lane];
      int v2 = KVt8[(size_t)s2 * 128 + 64 + lane];
      int v3 = KVt8[(size_t)s3 * 128 + 64 + lane];
      int v4 = KVt8[(size_t)s4 * 128 + 64 + lane];
      int v5 = KVt8[(size_t)s5 * 128 + 64 + lane];
      int v6 = KVt8[(size_t)s6 * 128 + 64 + lane];
      int v7 = KVt8[(size_t)s7 * 128 + 64 + lane];
      acc0 += a0 * __builtin_amdgcn_cvt_f32_fp8(v0, 0);
      acc1 += a1 * __builtin_amdgcn_cvt_f32_fp8(v1, 0);
      acc0 += a2 * __builtin_amdgcn_cvt_f32_fp8(v2, 0);
      acc1 += a3 * __builtin_amdgcn_cvt_f32_fp8(v3, 0);
      acc0 += a4 * __builtin_amdgcn_cvt_f32_fp8(v4, 0);
      acc1 += a5 * __builtin_amdgcn_cvt_f32_fp8(v5, 0);
      acc0 += a6 * __builtin_amdgcn_cvt_f32_fp8(v6, 0);
      acc1 += a7 * __builtin_amdgcn_cvt_f32_fp8(v7, 0);
    }
  }
  // ---- Sum(alpha) butterfly, once per node ----
  float ssum = ssl;
  ssum += __shfl_xor(ssum, 32, 64);
  ssum += __shfl_xor(ssum, 16, 64);
  ssum += __shfl_xor(ssum, 8, 64);
  ssum += __shfl_xor(ssum, 4, 64);
  ssum += __shfl_xor(ssum, 2, 64);
  ssum += __shfl_xor(ssum, 1, 64);
  __builtin_amdgcn_sched_barrier(0);
  // ---- skip projection (post-loop: Ws regs never live in the loop) ----
  float sk = bf2f(bs[lane]);
  {
    const uint4* wsp = (const uint4*)(WsT + (size_t)lane * 64);
#pragma unroll
    for (int i = 0; i < 8; ++i) {
      uint4 ws = wsp[i];
      float h0, h1;
      h0 = __shfl(hv, i * 8 + 0, 64); h1 = __shfl(hv, i * 8 + 1, 64);
      sk += h0 * lo16(ws.x) + h1 * hi16(ws.x);
      h0 = __shfl(hv, i * 8 + 2, 64); h1 = __shfl(hv, i * 8 + 3, 64);
      sk += h0 * lo16(ws.y) + h1 * hi16(ws.y);
      h0 = __shfl(hv, i * 8 + 4, 64); h1 = __shfl(hv, i * 8 + 5, 64);
      sk += h0 * lo16(ws.z) + h1 * hi16(ws.z);
      h0 = __shfl(hv, i * 8 + 6, 64); h1 = __shfl(hv, i * 8 + 7, 64);
      sk += h0 * lo16(ws.w) + h1 * hi16(ws.w);
    }
  }
  float val = (acc0 + acc1) / (ssum + 1e-16f) + sk;
  if (RES) val += hv;
  hout[(size_t)wid * 64 + lane] = f2bf(tanhf(val));
}

// ---------------- layer 3 projections (C=3): thread per node ----------------

__global__ __launch_bounds__(256) void k_gemm3(
    const unsigned short* __restrict__ hin,
    const unsigned short* __restrict__ Wq, const unsigned short* __restrict__ bq,
    const unsigned short* __restrict__ Wk, const unsigned short* __restrict__ bk,
    const unsigned short* __restrict__ Wv, const unsigned short* __restrict__ bv,
    const unsigned short* __restrict__ Ws, const unsigned short* __restrict__ bs,
    float* __restrict__ Q3, float* __restrict__ S3, uint4* __restrict__ KV3) {
  int d = blockIdx.x * 256 + threadIdx.x;
  if (d >= N_NODES) return;
  float q[3], kk[3], vv[3], ss[3];
  for (int c = 0; c < 3; ++c) {
    q[c] = bf2f(bq[c]);
    kk[c] = bf2f(bk[c]);
    vv[c] = bf2f(bv[c]);
    ss[c] = bf2f(bs[c]);
  }
  for (int j = 0; j < 64; ++j) {
    float hj = bf2f(hin[(size_t)d * 64 + j]);
    for (int c = 0; c < 3; ++c) {
      q[c] += hj * bf2f(Wq[j * 3 + c]);
      kk[c] += hj * bf2f(Wk[j * 3 + c]);
      vv[c] += hj * bf2f(Wv[j * 3 + c]);
      ss[c] += hj * bf2f(Ws[j * 3 + c]);
    }
  }
  for (int c = 0; c < 3; ++c) {
    Q3[d * 4 + c] = q[c];
    S3[d * 4 + c] = ss[c];
  }
  uint4 pk;
  pk.x = (unsigned)f2bf(kk[0]) | ((unsigned)f2bf(vv[0]) << 16);
  pk.y = (unsigned)f2bf(kk[1]) | ((unsigned)f2bf(vv[1]) << 16);
  pk.z = (unsigned)f2bf(kk[2]) | ((unsigned)f2bf(vv[2]) << 16);
  pk.w = 0;
  KV3[d] = pk;
}

// ---------------- edge pass, C=3: wave per dst, no-max ----------------

__global__ __launch_bounds__(256) void k_edge3(
    const int* __restrict__ off, const int* __restrict__ csr,
    const float* __restrict__ Q3, const float* __restrict__ S3,
    const uint4* __restrict__ KV3, const void* __restrict__ noise,
    void* __restrict__ out, const int* __restrict__ flag) {
  int w = threadIdx.x >> 6;
  int lane = threadIdx.x & 63;
  int wid = blockIdx.x * 4 + w;
  int base = off[wid];
  int deg = off[wid + 1] - base;
  float q0 = Q3[wid * 4], q1 = Q3[wid * 4 + 1], q2 = Q3[wid * 4 + 2];
  const float isq = 0.57735026919f;  // 1/sqrt(3)
  float ps = 0.f, p0 = 0.f, p1 = 0.f, p2 = 0.f;
  for (int j0 = 0; j0 < deg; j0 += 64) {
    int cnt = min(64, deg - j0);
    int src = csr[base + ((lane < cnt) ? (j0 + lane) : 0)];
    uint4 kv = KV3[src];  // 16-B gather from 1.6 MB (L2-resident)
    float sc = (q0 * lo16(kv.x) + q1 * lo16(kv.y) + q2 * lo16(kv.z)) * isq;
    sc = fminf(fmaxf(sc, -60.f), 60.f);
    float al = (lane < cnt) ? __expf(sc) : 0.f;
    ps += al;
    p0 += al * hi16(kv.x);
    p1 += al * hi16(kv.y);
    p2 += al * hi16(kv.z);
  }
#pragma unroll
  for (int o = 32; o > 0; o >>= 1) {
    ps += __shfl_xor(ps, o, 64);
    p0 += __shfl_xor(p0, o, 64);
    p1 += __shfl_xor(p1, o, 64);
    p2 += __shfl_xor(p2, o, 64);
  }
  if (lane == 0) {
    float inv = 1.f / (ps + 1e-16f);
    int isbf = *flag;
    float n0, n1, n2;
    if (isbf) {
      const unsigned short* nu = (const unsigned short*)noise;
      n0 = bf2f(nu[wid * 3 + 0]);
      n1 = bf2f(nu[wid * 3 + 1]);
      n2 = bf2f(nu[wid * 3 + 2]);
    } else {
      const float* nf = (const float*)noise;
      n0 = nf[wid * 3 + 0];
      n1 = nf[wid * 3 + 1];
      n2 = nf[wid * 3 + 2];
    }
    float r0 = p0 * inv + S3[wid * 4 + 0] + 0.1f * n0;
    float r1 = p1 * inv + S3[wid * 4 + 1] + 0.1f * n1;
    float r2 = p2 * inv + S3[wid * 4 + 2] + 0.1f * n2;
    if (isbf) {
      unsigned short* ou = (unsigned short*)out;
      ou[wid * 3 + 0] = f2bf(r0);
      ou[wid * 3 + 1] = f2bf(r1);
      ou[wid * 3 + 2] = f2bf(r2);
    } else {
      float* of = (float*)out;
      of[wid * 3 + 0] = r0;
      of[wid * 3 + 1] = r1;
      of[wid * 3 + 2] = r2;
    }
  }
}

// ---------------- launch ----------------

extern "C" void kernel_launch(void* const* d_in, const int* in_sizes, int n_in,
                              void* d_out, int out_size, void* d_ws, size_t ws_size,
                              hipStream_t stream) {
  const int* ei = (const int*)d_in[1];
  const int* srcs = ei;
  const int* dsts = ei + N_EDGES;

  // Workspace (NEED = 51668480 B — exactly the round-3-proven value):
  //   off @0 | csr @400128 | h @13200128 (bf16) | KVt8 @26000128 ([K64|V64] u8)
  //   Qt @38800128 (bf16 [N][64]) | wb @51600128 | flag @51668352
  //   (KVt8 region aliases CSR scratch pre-proj; Q3/S3/KV3 in layer 3)
  char* w = (char*)d_ws;
  int* off = (int*)w;
  int* csr = (int*)(w + 400128);
  unsigned short* h = (unsigned short*)(w + 13200128);
  char* kvbase = w + 26000128;
  unsigned char* KVt8 = (unsigned char*)kvbase;
  int* deg = (int*)kvbase;
  int* cursor = (int*)(kvbase + 524288);
  int* bsum = (int*)(kvbase + 1048576);
  int* bpref = (int*)(kvbase + 1056768);
  float* Q3 = (float*)kvbase;
  float* S3 = (float*)(kvbase + 2097152);
  uint4* KV3 = (uint4*)(kvbase + 4194304);
  unsigned short* Qt = (unsigned short*)(w + 38800128);
  unsigned short* wb = (unsigned short*)(w + 51600128);
  int* flag = (int*)(w + 51668352);
  const size_t NEED = 51668480;
  if (ws_size < NEED) return;

  unsigned short *Wb[3][4], *Bb[3][4];
  CvtArgs ca;
  {
    int o = 0, idx = 0;
    for (int l = 0; l < 3; ++l) {
      int dout = (l == 2) ? 3 : 64;
      for (int p = 0; p < 4; ++p) {
        ca.src[idx] = d_in[3 + l * 8 + p * 2];
        ca.dstoff[idx] = o;
        ca.n[idx] = 64 * dout;
        ca.tr[idx] = (l < 2) ? 1 : 0;  // layers 1-2: store W^T
        Wb[l][p] = wb + o;
        o += 64 * dout;
        idx++;
        ca.src[idx] = d_in[3 + l * 8 + p * 2 + 1];
        ca.dstoff[idx] = o;
        ca.n[idx] = dout;
        ca.tr[idx] = 0;
        Bb[l][p] = wb + o;
        o += dout;
        idx++;
      }
    }
  }

  k_detect<<<1, 256, 0, stream>>>((const unsigned short*)d_in[0], flag);
  k_prep<<<24 + NB + N_NODES * 64 / 8 / 256, 256, 0, stream>>>(ca, wb, d_in[0], h, deg, flag);

  k_hist<<<N_EDGES / 4 / 256, 256, 0, stream>>>(dsts, deg);
  k_scan1<<<NB, 256, 0, stream>>>(deg, bsum);
  k_scan2<<<1, 512, 0, stream>>>(bsum, bpref, off + N_NODES);
  k_scan3<<<NB, 256, 0, stream>>>(deg, bpref, off, cursor);
  k_scatter<<<N_EDGES / 4 / 256, 256, 0, stream>>>(srcs, dsts, cursor, csr);

  const int gw = N_NODES / 4;  // 25000 blocks x 4 waves
  // layer 1
  k_proj<<<gw, 256, 0, stream>>>(h, Wb[0][0], Bb[0][0], Wb[0][1], Bb[0][1],
                                 Wb[0][2], Bb[0][2], Qt, KVt8);
  k_edge64<false><<<gw, 256, 0, stream>>>(off, csr, h, Qt, Wb[0][3], Bb[0][3], KVt8, h);
  // layer 2
  k_proj<<<gw, 256, 0, stream>>>(h, Wb[1][0], Bb[1][0], Wb[1][1], Bb[1][1],
                                 Wb[1][2], Bb[1][2], Qt, KVt8);
  k_edge64<true><<<gw, 256, 0, stream>>>(off, csr, h, Qt, Wb[1][3], Bb[1][3], KVt8, h);
  // layer 3
  k_gemm3<<<NB, 256, 0, stream>>>(h, Wb[2][0], Bb[2][0], Wb[2][1], Bb[2][1],
                                  Wb[2][2], Bb[2][2], Wb[2][3], Bb[2][3], Q3, S3, KV3);
  k_edge3<<<gw, 256, 0, stream>>>(off, csr, Q3, S3, KV3, d_in[2], d_out, flag);
}